// Round 4
// baseline (592.533 us; speedup 1.0000x reference)
//
#include <hip/hip_runtime.h>
#include <stdint.h>

// ---------------------------------------------------------------------------
// LUT-quantized AlexNet on MI355X — f64 pre-quant numerics (absmax 0.0).
// R4: batch-pair float2 LUT table (ds_read_b64 serves 2 MACs), combined
// activation pair-bytes, fused zero kernel, pair-gather fc.
// ---------------------------------------------------------------------------

#define DI __device__ __forceinline__

constexpr size_t alup(size_t x){ return (x + 511) & ~(size_t)511; }
constexpr size_t O_SLOTS = 0;                            // 16 doubles
constexpr size_t O_IA0 = 512;                            // 24576 u8 (plain, conv0)
constexpr size_t O_IA1 = alup(O_IA0 + 24576);            // 65536 u8 pair-combined
constexpr size_t O_IA2 = alup(O_IA1 + 65536);            // 49152
constexpr size_t O_IA3 = alup(O_IA2 + 49152);            // 98304
constexpr size_t O_IA4 = alup(O_IA3 + 98304);            // 65536
constexpr size_t O_IA5 = alup(O_IA4 + 65536);            // 16384 u32 cmb
constexpr size_t O_IA6 = alup(O_IA5 + 16384);            // 16384
constexpr size_t O_IA7 = alup(O_IA6 + 16384);            // 16384
constexpr size_t O_WP0 = alup(O_IA7 + 16384);            // 864
constexpr size_t O_WP1 = alup(O_WP0 + 864);              // 55296
constexpr size_t O_WP2 = alup(O_WP1 + 55296);            // 331776
constexpr size_t O_WP3 = alup(O_WP2 + 331776);           // 442368
constexpr size_t O_WP4 = alup(O_WP3 + 442368);           // 294912
constexpr size_t O_A1  = alup(O_WP4 + 294912);           // 131072 f64 (1MB)
constexpr size_t O_A2  = alup(O_A1 + 1048576);           // 98304 f64
constexpr size_t O_A3  = alup(O_A2 + 786432);            // 196608 f64
constexpr size_t O_A4  = alup(O_A3 + 1572864);           // 131072 f64
constexpr size_t O_A5  = alup(O_A4 + 1048576);           // 32768 f64
constexpr size_t O_H5  = alup(O_A5 + 262144);            // 32768 f64
constexpr size_t O_H6  = alup(O_H5 + 262144);            // 32768 f64
constexpr size_t O_P   = alup(O_H6 + 262144);            // P1..P4 f64, 6.8MB
constexpr size_t O_P1  = O_P;                            // 393216 d (3145728B)
constexpr size_t O_P2  = O_P1 + 3145728;                 // 196608 d
constexpr size_t O_P3  = O_P2 + 1572864;                 // 131072 d
constexpr size_t O_P4  = O_P3 + 1048576;                 // 131072 d
constexpr int    PZ_D4 = 212992;                         // total P doubles /4

// slots(double): [0..7]=absmax(w0..w7), [8]=absmax(x), [9..15]=absmax act 1..7

DI double getscale(const double* slots, int i){ return fmax(slots[i] / 7.0, 1e-8); }
DI int quant_idx_r(double v, double r){ // r = 1/s
  double q = fmin(fmax(rint(v * r), -8.0), 7.0);
  return (int)q + 8;
}
DI void atomicMaxD(double* addr, double v){ // v >= 0
  atomicMax((unsigned long long*)addr, (unsigned long long)__double_as_longlong(v));
}

// zero slots + all P buffers in one launch
__global__ __launch_bounds__(256) void k_zero_all(double4* pz, double* slots){
  int i = blockIdx.x*256 + threadIdx.x;
  if (i < PZ_D4){ double4 z; z.x=z.y=z.z=z.w=0.0; pz[i] = z; }
  else if (i - PZ_D4 < 16) slots[i - PZ_D4] = 0.0;
}

__global__ __launch_bounds__(256) void k_wmax(
    const float* w0, const float* w1, const float* w2, const float* w3, const float* w4,
    const float* w5, const float* w6, const float* w7, const float* x, double* slots)
{
  const int sizes[9] = {1728,110592,663552,884736,589824,16777216,16777216,40960,24576};
  const int cum[10]  = {0,1,5,26,53,71,583,1095,1097,1098};
  int bid = blockIdx.x;
  int seg = 0;
  #pragma unroll
  for (int s2 = 0; s2 < 9; ++s2) if (bid >= cum[s2+1]) seg = s2+1;
  const float* p;
  switch (seg){
    case 0: p = w0; break; case 1: p = w1; break; case 2: p = w2; break;
    case 3: p = w3; break; case 4: p = w4; break; case 5: p = w5; break;
    case 6: p = w6; break; case 7: p = w7; break; default: p = x; break;
  }
  int n = sizes[seg];
  long base = (long)(bid - cum[seg]) * 32768;
  float m = 0.f;
  for (long i = base + threadIdx.x * 4; i < base + 32768 && i < (long)n; i += 1024){
    float4 v = *(const float4*)(p + i);
    m = fmaxf(m, fmaxf(fmaxf(fabsf(v.x), fabsf(v.y)), fmaxf(fabsf(v.z), fabsf(v.w))));
  }
  #pragma unroll
  for (int off = 32; off; off >>= 1) m = fmaxf(m, __shfl_xor(m, off, 64));
  __shared__ float red[4];
  if ((threadIdx.x & 63) == 0) red[threadIdx.x >> 6] = m;
  __syncthreads();
  if (threadIdx.x == 0)
    atomicMaxD(&slots[seg], (double)fmaxf(fmaxf(red[0], red[1]), fmaxf(red[2], red[3])));
}

// quantize conv weights (nibble-packed, nibble j = o%8) and x (byte-packed).
__global__ __launch_bounds__(256) void k_wq(
    const float* w0, const float* w1, const float* w2, const float* w3, const float* w4,
    const float* x, const double* slots, uint8_t* ws)
{
  int item = blockIdx.x * 256 + threadIdx.x;
  if (item < 281304){
    const float* w; uint32_t* wp; int K; int r; double s;
    if (item < 216)        { w=w0; wp=(uint32_t*)(ws+O_WP0); K=27;   r=item;        s=getscale(slots,0); }
    else if (item < 14040) { w=w1; wp=(uint32_t*)(ws+O_WP1); K=576;  r=item-216;    s=getscale(slots,1); }
    else if (item < 96984) { w=w2; wp=(uint32_t*)(ws+O_WP2); K=1728; r=item-14040;  s=getscale(slots,2); }
    else if (item < 207576){ w=w3; wp=(uint32_t*)(ws+O_WP3); K=3456; r=item-96984;  s=getscale(slots,3); }
    else                   { w=w4; wp=(uint32_t*)(ws+O_WP4); K=2304; r=item-207576; s=getscale(slots,4); }
    double rs = 1.0 / s;
    int og = r / K, k = r % K;
    uint32_t pack = 0;
    #pragma unroll
    for (int j = 0; j < 8; ++j){
      double wv = (double)w[(size_t)(og*8 + j)*K + k];
      pack |= (uint32_t)quant_idx_r(wv, rs) << (4*j);
    }
    wp[og*K + k] = pack;
  } else if (item < 287448){
    int i2 = item - 281304;
    double rs = 1.0 / getscale(slots, 8);
    uint32_t pack = 0;
    #pragma unroll
    for (int r2 = 0; r2 < 4; ++r2)
      pack |= (uint32_t)quant_idx_r((double)x[i2*4 + r2], rs) << (8*r2);
    ((uint32_t*)(ws + O_IA0))[i2] = pack;
  }
}

// conv0: direct (C=3,K=27), fused relu+maxpool+absmax. grid 512 = 8b x 64o.
__global__ __launch_bounds__(256) void k_conv0(
    const uint8_t* __restrict__ ia0, const uint32_t* __restrict__ wp0,
    const float* __restrict__ lut_g, const float* __restrict__ bias,
    double* slots, double* __restrict__ a1)
{
  __shared__ float lutT[256];
  int tid = threadIdx.x;
  lutT[(tid & 15)*16 + (tid >> 4)] = lut_g[tid];
  __syncthreads();
  int b = blockIdx.x >> 6, o = blockIdx.x & 63;
  int yp = tid >> 4, xp = tid & 15;
  double scale = getscale(slots, 8) * getscale(slots, 0);
  double bo = (double)bias[o];
  double pool = 0.0;
  #pragma unroll
  for (int dy = 0; dy < 2; ++dy)
  #pragma unroll
  for (int dx = 0; dx < 2; ++dx){
    int y = yp*2 + dy, x2 = xp*2 + dx;
    double sum = 0.0;
    #pragma unroll
    for (int c = 0; c < 3; ++c)
      #pragma unroll
      for (int ty = 0; ty < 3; ++ty)
        #pragma unroll
        for (int tx = 0; tx < 3; ++tx){
          int yy = y + ty - 1, xx = x2 + tx - 1;
          int ia = 8;
          if (yy >= 0 && yy < 32 && xx >= 0 && xx < 32)
            ia = ia0[((b*3 + c)*32 + yy)*32 + xx];
          uint32_t sw = wp0[(o >> 3)*27 + c*9 + ty*3 + tx];
          int iw = (sw >> ((o & 7)*4)) & 15;
          sum += (double)lutT[iw*16 + ia];
        }
    pool = fmax(pool, fmax(sum*scale + bo, 0.0));
  }
  a1[((b*64 + o)*16 + yp)*16 + xp] = pool;
  double m = pool;
  #pragma unroll
  for (int off = 32; off; off >>= 1) m = fmax(m, __shfl_xor(m, off, 64));
  __shared__ double red[4];
  if ((tid & 63) == 0) red[tid >> 6] = m;
  __syncthreads();
  if (tid == 0) atomicMaxD(&slots[9], fmax(fmax(red[0],red[1]), fmax(red[2],red[3])));
}

// generic 3x3 conv, batch-pair gathers. Block = 4 waves = 4 batch-pairs,
// 8 outputs (ob), CT channels (ks), SP row-tiles. One ds_read_b64 = 2 MACs.
template<int C, int O, int H, int W, int CT, int ROWS, int SP, int KS>
__global__ __launch_bounds__(256) void k_convP(
    const uint8_t* __restrict__ iain, const uint32_t* __restrict__ wp,
    const float* __restrict__ lut_g, double* __restrict__ P)
{
  constexpr int AW = W + 2, AH = ROWS + 2;
  __shared__ float2 pairT[4096];           // [iw][ia1][ia2] -> (lut[ia1][iw], lut[ia2][iw])
  __shared__ uint32_t wps[CT*9];
  __shared__ uint8_t actsC[4*CT*AH*AW];    // combined pair bytes
  int tid = threadIdx.x;
  int bx = blockIdx.x;
  int ks = bx % KS; int rem = bx / KS;
  int ob = rem % (O/8); int sp = rem / (O/8);
  for (int e = tid; e < 4096; e += 256){
    int iw = e >> 8, a1 = (e >> 4) & 15, a2 = e & 15;
    pairT[e] = make_float2(lut_g[a1*16 + iw], lut_g[a2*16 + iw]);
  }
  for (int i = tid; i < CT*9; i += 256)
    wps[i] = wp[(size_t)ob*(C*9) + ks*CT*9 + i];
  constexpr int ATOT = 4*CT*AH*AW;
  for (int i = tid; i < ATOT; i += 256){
    int p2 = i / (CT*AH*AW);
    int r2 = i % (CT*AH*AW);
    int ct = r2 / (AH*AW);
    int r = (r2 / AW) % AH;
    int cc = r2 % AW;
    int y = sp*ROWS + r - 1, x2 = cc - 1;
    uint8_t v = 136;  // pad pair: (8,8)
    if (y >= 0 && y < H && x2 >= 0 && x2 < W)
      v = iain[(((size_t)p2*C + ks*CT + ct)*H + y)*W + x2];
    actsC[i] = v;
  }
  __syncthreads();
  int p = tid >> 6, lane = tid & 63;
  int ly = lane / W, lx = lane % W;
  double acc0[8] = {0,0,0,0,0,0,0,0};
  double acc1[8] = {0,0,0,0,0,0,0,0};
  #pragma unroll 1
  for (int ct = 0; ct < CT; ++ct){
    int abase = ((p*CT + ct)*AH + ly)*AW + lx;
    #pragma unroll
    for (int ty = 0; ty < 3; ++ty)
    #pragma unroll
    for (int tx = 0; tx < 3; ++tx){
      int c = actsC[abase + ty*AW + tx];
      uint32_t sw = (uint32_t)__builtin_amdgcn_readfirstlane((int)wps[ct*9 + ty*3 + tx]);
      #pragma unroll
      for (int j = 0; j < 8; ++j){
        float2 v = pairT[(((sw >> (4*j)) & 15u) << 8) + c];
        acc0[j] += (double)v.x;
        acc1[j] += (double)v.y;
      }
    }
  }
  int y = sp*ROWS + ly;
  #pragma unroll
  for (int j = 0; j < 8; ++j){
    size_t base = (((size_t)(2*p)*O + ob*8 + j)*H + y)*W + lx;
    atomicAdd(&P[base], acc0[j]);
    atomicAdd(&P[base + (size_t)O*H*W], acc1[j]);
  }
}

// P + bias + relu (+pool) + write act f64 + absmax.
template<int O, int Hc, int Wc, bool POOL>
__global__ __launch_bounds__(256) void k_post(
    const double* __restrict__ P, const float* __restrict__ bias,
    double* __restrict__ aout, double* slots, int sx_slot, int sw_slot, int ma_slot)
{
  constexpr int Ho = POOL ? Hc/2 : Hc, Wo = POOL ? Wc/2 : Wc;
  int i = blockIdx.x*256 + threadIdx.x;
  int x2 = i % Wo, y = (i / Wo) % Ho, o = (i / (Wo*Ho)) % O, b = i / (Wo*Ho*O);
  double scale = getscale(slots, sx_slot) * getscale(slots, sw_slot);
  double bo = (double)bias[o];
  double res;
  if (POOL){
    double p = 0.0;
    #pragma unroll
    for (int dy = 0; dy < 2; ++dy)
    #pragma unroll
    for (int dx = 0; dx < 2; ++dx){
      double s = P[(((size_t)b*O + o)*Hc + y*2+dy)*Wc + x2*2+dx];
      p = fmax(p, fmax(s*scale + bo, 0.0));
    }
    res = p;
  } else {
    double s = P[(((size_t)b*O + o)*Hc + y)*Wc + x2];
    res = fmax(s*scale + bo, 0.0);
  }
  aout[i] = res;
  double m = res;
  #pragma unroll
  for (int off = 32; off; off >>= 1) m = fmax(m, __shfl_xor(m, off, 64));
  __shared__ double red[4];
  if ((threadIdx.x & 63) == 0) red[threadIdx.x >> 6] = m;
  __syncthreads();
  if (threadIdx.x == 0)
    atomicMaxD(&slots[ma_slot], fmax(fmax(red[0],red[1]), fmax(red[2],red[3])));
}

// quantize activations into combined pair bytes [pair][C][H][W].
__global__ __launch_bounds__(256) void k_aq_convP(
    const double* __restrict__ in, uint8_t* __restrict__ out,
    const double* slots, int slot, int CHW, int n)
{
  int i = blockIdx.x*256 + threadIdx.x;
  if (i >= n) return;
  double rs = 1.0 / getscale(slots, slot);
  int p = i / CHW, rr = i % CHW;
  int q1 = quant_idx_r(in[(size_t)(2*p)*CHW + rr], rs);
  int q2 = quant_idx_r(in[(size_t)(2*p+1)*CHW + rr], rs);
  out[i] = (uint8_t)((q1 << 4) | q2);
}

// fc-input quant: [8][4096] f64 -> cmb[f] u32 (4 pair bytes).
__global__ __launch_bounds__(256) void k_aq_fcP(
    const double* __restrict__ in, uint32_t* __restrict__ cmb,
    const double* slots, int slot)
{
  int f = blockIdx.x*256 + threadIdx.x; // 4096
  double rs = 1.0 / getscale(slots, slot);
  uint32_t r = 0;
  #pragma unroll
  for (int p = 0; p < 4; ++p){
    int q1 = quant_idx_r(in[(size_t)(2*p)*4096 + f], rs);
    int q2 = quant_idx_r(in[(size_t)(2*p+1)*4096 + f], rs);
    r |= (uint32_t)((q1 << 4) | q2) << (8*p);
  }
  cmb[f] = r;
}

// fc 4096->4096, 1 output/wave, pair gathers, f64 accum.
template<bool RELU>
__global__ __launch_bounds__(256) void k_fcP(
    const float* __restrict__ Wm, const float* __restrict__ bias,
    const uint32_t* __restrict__ cmb, const float* __restrict__ lut_g,
    double* __restrict__ out, double* slots, int sx_slot, int sw_slot, int ma_slot)
{
  __shared__ float2 pairT[4096];
  __shared__ uint32_t cmbS[4096];
  __shared__ double red[4];
  int tid = threadIdx.x;
  for (int e = tid; e < 4096; e += 256){
    int iw = e >> 8, a1 = (e >> 4) & 15, a2 = e & 15;
    pairT[e] = make_float2(lut_g[a1*16 + iw], lut_g[a2*16 + iw]);
  }
  for (int i = tid; i < 4096; i += 256) cmbS[i] = cmb[i];
  __syncthreads();
  double sw = getscale(slots, sw_slot);
  double rsw = 1.0 / sw;
  double scale = getscale(slots, sx_slot) * sw;
  int wid = tid >> 6, lane = tid & 63;
  int o = blockIdx.x*4 + wid;
  const float* wr = Wm + (size_t)o*4096;
  double acc[8] = {0,0,0,0,0,0,0,0};
  #pragma unroll 2
  for (int ch = 0; ch < 64; ++ch){
    int f = ch*64 + lane;
    unsigned iw = (unsigned)quant_idx_r((double)wr[f], rsw);
    const float2* row = &pairT[iw << 8];
    uint32_t cb = cmbS[f];
    float2 v0 = row[cb & 255];         acc[0] += (double)v0.x; acc[1] += (double)v0.y;
    float2 v1 = row[(cb >> 8) & 255];  acc[2] += (double)v1.x; acc[3] += (double)v1.y;
    float2 v2 = row[(cb >> 16) & 255]; acc[4] += (double)v2.x; acc[5] += (double)v2.y;
    float2 v3 = row[cb >> 24];         acc[6] += (double)v3.x; acc[7] += (double)v3.y;
  }
  #pragma unroll
  for (int off = 32; off; off >>= 1)
    #pragma unroll
    for (int b2 = 0; b2 < 8; ++b2) acc[b2] += __shfl_xor(acc[b2], off, 64);
  if (lane == 0){
    double m = 0.0;
    double bo = (double)bias[o];
    #pragma unroll
    for (int b2 = 0; b2 < 8; ++b2){
      double h = acc[b2]*scale + bo;
      if (RELU) h = fmax(h, 0.0);
      out[(size_t)b2*4096 + o] = h;
      m = fmax(m, fabs(h));
    }
    red[wid] = m;
  }
  __syncthreads();
  if (tid == 0)
    atomicMaxD(&slots[ma_slot], fmax(fmax(red[0],red[1]), fmax(red[2],red[3])));
}

// final fc 4096->10 (no relu), writes d_out [8,10] as f32.
__global__ __launch_bounds__(256) void k_fc7P(
    const float* __restrict__ Wm, const float* __restrict__ bias,
    const uint32_t* __restrict__ cmb, const float* __restrict__ lut_g,
    float* __restrict__ out, const double* slots)
{
  __shared__ float2 pairT[4096];
  __shared__ uint32_t cmbS[4096];
  __shared__ double red[4][8];
  int tid = threadIdx.x;
  for (int e = tid; e < 4096; e += 256){
    int iw = e >> 8, a1 = (e >> 4) & 15, a2 = e & 15;
    pairT[e] = make_float2(lut_g[a1*16 + iw], lut_g[a2*16 + iw]);
  }
  for (int i = tid; i < 4096; i += 256) cmbS[i] = cmb[i];
  __syncthreads();
  double sw = getscale(slots, 7);
  double rsw = 1.0 / sw;
  double scale = getscale(slots, 15) * sw;
  int o = blockIdx.x;
  const float* wr = Wm + (size_t)o*4096;
  double acc[8] = {0,0,0,0,0,0,0,0};
  for (int ch = 0; ch < 16; ++ch){
    int f = ch*256 + tid;
    unsigned iw = (unsigned)quant_idx_r((double)wr[f], rsw);
    const float2* row = &pairT[iw << 8];
    uint32_t cb = cmbS[f];
    float2 v0 = row[cb & 255];         acc[0] += (double)v0.x; acc[1] += (double)v0.y;
    float2 v1 = row[(cb >> 8) & 255];  acc[2] += (double)v1.x; acc[3] += (double)v1.y;
    float2 v2 = row[(cb >> 16) & 255]; acc[4] += (double)v2.x; acc[5] += (double)v2.y;
    float2 v3 = row[cb >> 24];         acc[6] += (double)v3.x; acc[7] += (double)v3.y;
  }
  int wid = tid >> 6, lane = tid & 63;
  #pragma unroll
  for (int off = 32; off; off >>= 1)
    #pragma unroll
    for (int b2 = 0; b2 < 8; ++b2) acc[b2] += __shfl_xor(acc[b2], off, 64);
  if (lane == 0){
    #pragma unroll
    for (int b2 = 0; b2 < 8; ++b2) red[wid][b2] = acc[b2];
  }
  __syncthreads();
  if (tid < 8){
    double v = red[0][tid] + red[1][tid] + red[2][tid] + red[3][tid];
    out[tid*10 + o] = (float)(v*scale + (double)bias[o]);
  }
}

// ---------------- launcher ----------------
extern "C" void kernel_launch(void* const* d_in, const int* in_sizes, int n_in,
                              void* d_out, int out_size, void* d_ws, size_t ws_size,
                              hipStream_t stream)
{
  (void)in_sizes; (void)n_in; (void)out_size; (void)ws_size;
  const float* x  = (const float*)d_in[0];
  const float* w0 = (const float*)d_in[1];  const float* b0 = (const float*)d_in[2];
  const float* w1 = (const float*)d_in[3];  const float* b1 = (const float*)d_in[4];
  const float* w2 = (const float*)d_in[5];  const float* b2 = (const float*)d_in[6];
  const float* w3 = (const float*)d_in[7];  const float* b3 = (const float*)d_in[8];
  const float* w4 = (const float*)d_in[9];  const float* b4 = (const float*)d_in[10];
  const float* w5 = (const float*)d_in[11]; const float* b5 = (const float*)d_in[12];
  const float* w6 = (const float*)d_in[13]; const float* b6 = (const float*)d_in[14];
  const float* w7 = (const float*)d_in[15]; const float* b7 = (const float*)d_in[16];
  const float* luts = (const float*)d_in[17];

  uint8_t* ws = (uint8_t*)d_ws;
  double* slots = (double*)(ws + O_SLOTS);
  const uint8_t* IA0 = ws + O_IA0;
  uint8_t *IA1 = ws + O_IA1, *IA2 = ws + O_IA2, *IA3 = ws + O_IA3, *IA4 = ws + O_IA4;
  uint32_t *IA5 = (uint32_t*)(ws + O_IA5);
  uint32_t *IA6 = (uint32_t*)(ws + O_IA6);
  uint32_t *IA7 = (uint32_t*)(ws + O_IA7);
  const uint32_t* WP0 = (const uint32_t*)(ws + O_WP0);
  const uint32_t* WP1 = (const uint32_t*)(ws + O_WP1);
  const uint32_t* WP2 = (const uint32_t*)(ws + O_WP2);
  const uint32_t* WP3 = (const uint32_t*)(ws + O_WP3);
  const uint32_t* WP4 = (const uint32_t*)(ws + O_WP4);
  double *A1 = (double*)(ws + O_A1), *A2 = (double*)(ws + O_A2), *A3 = (double*)(ws + O_A3);
  double *A4 = (double*)(ws + O_A4), *A5 = (double*)(ws + O_A5);
  double *H5 = (double*)(ws + O_H5), *H6 = (double*)(ws + O_H6);
  double *P1 = (double*)(ws + O_P1), *P2 = (double*)(ws + O_P2);
  double *P3 = (double*)(ws + O_P3), *P4 = (double*)(ws + O_P4);

  k_zero_all<<<833, 256, 0, stream>>>((double4*)(ws + O_P), slots);
  k_wmax<<<1098, 256, 0, stream>>>(w0,w1,w2,w3,w4,w5,w6,w7,x,slots);
  k_wq<<<1123, 256, 0, stream>>>(w0,w1,w2,w3,w4,x,slots,ws);

  // L0: conv(3->64,32x32)+relu+pool -> A1 [8,64,16,16] f64, absmax->slot9
  k_conv0<<<512, 256, 0, stream>>>(IA0, WP0, luts + 0, b0, slots, A1);
  k_aq_convP<<<256, 256, 0, stream>>>(A1, IA1, slots, 9, 16384, 65536);

  // L1: conv(64->192,16x16)+pool. CT=8,KS=8,SP=4 -> grid 768
  k_convP<64,192,16,16,8,4,4,8><<<768, 256, 0, stream>>>(IA1, WP1, luts + 256, P1);
  k_post<192,16,16,true><<<384, 256, 0, stream>>>(P1, b1, A2, slots, 9, 1, 10);
  k_aq_convP<<<192, 256, 0, stream>>>(A2, IA2, slots, 10, 12288, 49152);

  // L2: conv(192->384,8x8). CT=8,KS=24 -> grid 1152
  k_convP<192,384,8,8,8,8,1,24><<<1152, 256, 0, stream>>>(IA2, WP2, luts + 512, P2);
  k_post<384,8,8,false><<<768, 256, 0, stream>>>(P2, b2, A3, slots, 10, 2, 11);
  k_aq_convP<<<384, 256, 0, stream>>>(A3, IA3, slots, 11, 24576, 98304);

  // L3: conv(384->256,8x8). CT=12,KS=32 -> grid 1024
  k_convP<384,256,8,8,12,8,1,32><<<1024, 256, 0, stream>>>(IA3, WP3, luts + 768, P3);
  k_post<256,8,8,false><<<512, 256, 0, stream>>>(P3, b3, A4, slots, 11, 3, 12);
  k_aq_convP<<<256, 256, 0, stream>>>(A4, IA4, slots, 12, 16384, 65536);

  // L4: conv(256->256,8x8)+pool. CT=8,KS=32 -> grid 1024
  k_convP<256,256,8,8,8,8,1,32><<<1024, 256, 0, stream>>>(IA4, WP4, luts + 1024, P4);
  k_post<256,8,8,true><<<128, 256, 0, stream>>>(P4, b4, A5, slots, 12, 4, 13);
  k_aq_fcP<<<16, 256, 0, stream>>>(A5, IA5, slots, 13);

  // FC
  k_fcP<true><<<1024, 256, 0, stream>>>(w5, b5, IA5, luts + 1280, H5, slots, 13, 5, 14);
  k_aq_fcP<<<16, 256, 0, stream>>>(H5, IA6, slots, 14);
  k_fcP<true><<<1024, 256, 0, stream>>>(w6, b6, IA6, luts + 1536, H6, slots, 14, 6, 15);
  k_aq_fcP<<<16, 256, 0, stream>>>(H6, IA7, slots, 15);
  k_fc7P<<<10, 256, 0, stream>>>(w7, b7, IA7, luts + 1792, (float*)d_out, slots);
}

// Round 5
// 502.998 us; speedup vs baseline: 1.1780x; 1.1780x over previous
//
#include <hip/hip_runtime.h>
#include <stdint.h>

// ---------------------------------------------------------------------------
// LUT-quantized AlexNet on MI355X — f64 pre-quant numerics (absmax 0.0).
// R5: R3 structure + f64 LUT in LDS (2KB, kills the per-MAC cvt), 4 waves
// share one k-slice's acts (32 outputs/block), fused zero kernel, f64-LUT fc.
// ---------------------------------------------------------------------------

#define DI __device__ __forceinline__

constexpr size_t alup(size_t x){ return (x + 511) & ~(size_t)511; }
constexpr size_t O_SLOTS = 0;                            // 16 doubles
constexpr size_t O_IA0 = 512;                            // 24576 u8
constexpr size_t O_IA1 = alup(O_IA0 + 24576);            // 131072 u8
constexpr size_t O_IA2 = alup(O_IA1 + 131072);           // 98304 u8
constexpr size_t O_IA3 = alup(O_IA2 + 98304);            // 196608 u8
constexpr size_t O_IA4 = alup(O_IA3 + 196608);           // 131072 u8
constexpr size_t O_IA5 = alup(O_IA4 + 131072);           // 32768 (lo16K|hi16K)
constexpr size_t O_IA6 = alup(O_IA5 + 32768);            // 32768
constexpr size_t O_IA7 = alup(O_IA6 + 32768);            // 32768
constexpr size_t O_WP0 = alup(O_IA7 + 32768);            // 864
constexpr size_t O_WP1 = alup(O_WP0 + 864);              // 55296
constexpr size_t O_WP2 = alup(O_WP1 + 55296);            // 331776
constexpr size_t O_WP3 = alup(O_WP2 + 331776);           // 442368
constexpr size_t O_WP4 = alup(O_WP3 + 442368);           // 294912
constexpr size_t O_A1  = alup(O_WP4 + 294912);           // 131072 f64
constexpr size_t O_A2  = alup(O_A1 + 1048576);           // 98304 f64
constexpr size_t O_A3  = alup(O_A2 + 786432);            // 196608 f64
constexpr size_t O_A4  = alup(O_A3 + 1572864);           // 131072 f64
constexpr size_t O_A5  = alup(O_A4 + 1048576);           // 32768 f64
constexpr size_t O_H5  = alup(O_A5 + 262144);            // 32768 f64
constexpr size_t O_H6  = alup(O_H5 + 262144);            // 32768 f64
constexpr size_t O_P1  = alup(O_H6 + 262144);            // [8,192,16,16] f64
constexpr size_t O_P2  = O_P1 + 3145728;                 // [8,384,8,8] f64
constexpr size_t O_P3  = O_P2 + 1572864;                 // [8,256,8,8] f64
constexpr size_t O_P4  = O_P3 + 1048576;                 // [8,256,8,8] f64
constexpr int    PZ_D4 = 212992;                         // total P doubles / 4

// slots(double): [0..7]=absmax(w0..w7), [8]=absmax(x), [9..15]=absmax act 1..7

DI double getscale(const double* slots, int i){ return fmax(slots[i] / 7.0, 1e-8); }
DI int quant_idx_r(double v, double r){ // r = 1/s
  double q = fmin(fmax(rint(v * r), -8.0), 7.0);
  return (int)q + 8;
}
DI void atomicMaxD(double* addr, double v){ // v >= 0
  atomicMax((unsigned long long*)addr, (unsigned long long)__double_as_longlong(v));
}

// zero slots + all P buffers in one launch
__global__ __launch_bounds__(256) void k_zero_all(double4* pz, double* slots){
  int i = blockIdx.x*256 + threadIdx.x;
  if (i < PZ_D4){ double4 z; z.x=z.y=z.z=z.w=0.0; pz[i] = z; }
  else if (i - PZ_D4 < 16) slots[i - PZ_D4] = 0.0;
}

__global__ __launch_bounds__(256) void k_wmax(
    const float* w0, const float* w1, const float* w2, const float* w3, const float* w4,
    const float* w5, const float* w6, const float* w7, const float* x, double* slots)
{
  const int sizes[9] = {1728,110592,663552,884736,589824,16777216,16777216,40960,24576};
  const int cum[10]  = {0,1,5,26,53,71,583,1095,1097,1098};
  int bid = blockIdx.x;
  int seg = 0;
  #pragma unroll
  for (int s2 = 0; s2 < 9; ++s2) if (bid >= cum[s2+1]) seg = s2+1;
  const float* p;
  switch (seg){
    case 0: p = w0; break; case 1: p = w1; break; case 2: p = w2; break;
    case 3: p = w3; break; case 4: p = w4; break; case 5: p = w5; break;
    case 6: p = w6; break; case 7: p = w7; break; default: p = x; break;
  }
  int n = sizes[seg];
  long base = (long)(bid - cum[seg]) * 32768;
  float m = 0.f;
  for (long i = base + threadIdx.x * 4; i < base + 32768 && i < (long)n; i += 1024){
    float4 v = *(const float4*)(p + i);
    m = fmaxf(m, fmaxf(fmaxf(fabsf(v.x), fabsf(v.y)), fmaxf(fabsf(v.z), fabsf(v.w))));
  }
  #pragma unroll
  for (int off = 32; off; off >>= 1) m = fmaxf(m, __shfl_xor(m, off, 64));
  __shared__ float red[4];
  if ((threadIdx.x & 63) == 0) red[threadIdx.x >> 6] = m;
  __syncthreads();
  if (threadIdx.x == 0)
    atomicMaxD(&slots[seg], (double)fmaxf(fmaxf(red[0], red[1]), fmaxf(red[2], red[3])));
}

// quantize conv weights (nibble-packed, nibble j = o%8) and x (byte-packed).
__global__ __launch_bounds__(256) void k_wq(
    const float* w0, const float* w1, const float* w2, const float* w3, const float* w4,
    const float* x, const double* slots, uint8_t* ws)
{
  int item = blockIdx.x * 256 + threadIdx.x;
  if (item < 281304){
    const float* w; uint32_t* wp; int K; int r; double s;
    if (item < 216)        { w=w0; wp=(uint32_t*)(ws+O_WP0); K=27;   r=item;        s=getscale(slots,0); }
    else if (item < 14040) { w=w1; wp=(uint32_t*)(ws+O_WP1); K=576;  r=item-216;    s=getscale(slots,1); }
    else if (item < 96984) { w=w2; wp=(uint32_t*)(ws+O_WP2); K=1728; r=item-14040;  s=getscale(slots,2); }
    else if (item < 207576){ w=w3; wp=(uint32_t*)(ws+O_WP3); K=3456; r=item-96984;  s=getscale(slots,3); }
    else                   { w=w4; wp=(uint32_t*)(ws+O_WP4); K=2304; r=item-207576; s=getscale(slots,4); }
    double rs = 1.0 / s;
    int og = r / K, k = r % K;
    uint32_t pack = 0;
    #pragma unroll
    for (int j = 0; j < 8; ++j){
      double wv = (double)w[(size_t)(og*8 + j)*K + k];
      pack |= (uint32_t)quant_idx_r(wv, rs) << (4*j);
    }
    wp[og*K + k] = pack;
  } else if (item < 287448){
    int i2 = item - 281304;
    double rs = 1.0 / getscale(slots, 8);
    uint32_t pack = 0;
    #pragma unroll
    for (int r2 = 0; r2 < 4; ++r2)
      pack |= (uint32_t)quant_idx_r((double)x[i2*4 + r2], rs) << (8*r2);
    ((uint32_t*)(ws + O_IA0))[i2] = pack;
  }
}

// conv0: direct (C=3,K=27), fused relu+maxpool+absmax. grid 512 = 8b x 64o.
__global__ __launch_bounds__(256) void k_conv0(
    const uint8_t* __restrict__ ia0, const uint32_t* __restrict__ wp0,
    const float* __restrict__ lut_g, const float* __restrict__ bias,
    double* slots, double* __restrict__ a1)
{
  __shared__ double lutT[256];  // [iw][ia]
  int tid = threadIdx.x;
  lutT[(tid & 15)*16 + (tid >> 4)] = (double)lut_g[tid];
  __syncthreads();
  int b = blockIdx.x >> 6, o = blockIdx.x & 63;
  int yp = tid >> 4, xp = tid & 15;
  double scale = getscale(slots, 8) * getscale(slots, 0);
  double bo = (double)bias[o];
  double pool = 0.0;
  #pragma unroll
  for (int dy = 0; dy < 2; ++dy)
  #pragma unroll
  for (int dx = 0; dx < 2; ++dx){
    int y = yp*2 + dy, x2 = xp*2 + dx;
    double sum = 0.0;
    #pragma unroll
    for (int c = 0; c < 3; ++c)
      #pragma unroll
      for (int ty = 0; ty < 3; ++ty)
        #pragma unroll
        for (int tx = 0; tx < 3; ++tx){
          int yy = y + ty - 1, xx = x2 + tx - 1;
          int ia = 8;
          if (yy >= 0 && yy < 32 && xx >= 0 && xx < 32)
            ia = ia0[((b*3 + c)*32 + yy)*32 + xx];
          uint32_t sw = wp0[(o >> 3)*27 + c*9 + ty*3 + tx];
          int iw = (sw >> ((o & 7)*4)) & 15;
          sum += lutT[iw*16 + ia];
        }
    pool = fmax(pool, fmax(sum*scale + bo, 0.0));
  }
  a1[((b*64 + o)*16 + yp)*16 + xp] = pool;
  double m = pool;
  #pragma unroll
  for (int off = 32; off; off >>= 1) m = fmax(m, __shfl_xor(m, off, 64));
  __shared__ double red[4];
  if ((tid & 63) == 0) red[tid >> 6] = m;
  __syncthreads();
  if (tid == 0) atomicMaxD(&slots[9], fmax(fmax(red[0],red[1]), fmax(red[2],red[3])));
}

// generic 3x3 conv. Block = 4 waves = 4 output-groups (32 outs), one k-slice.
// lanes = 64 spatial. f64 LDS LUT gather (ds_read_b64) + add_f64; atomicAdd P.
template<int C, int O, int H, int W, int CT, int ROWS, int SP, int KS>
__global__ __launch_bounds__(256) void k_conv(
    const uint8_t* __restrict__ iain, const uint32_t* __restrict__ wp,
    const float* __restrict__ lut_g, double* __restrict__ P)
{
  constexpr int KT = CT*9;
  constexpr int AW = W + 2, AH = ROWS + 2;
  __shared__ double lutT[256];            // [iw][ia] f64, 2KB
  __shared__ uint32_t wps[4*KT];          // [wave][KT]
  __shared__ uint8_t acts[CT*AH*AW];
  int tid = threadIdx.x;
  int bx = blockIdx.x;
  int ks = bx % KS; int rem = bx / KS;
  int ob = rem % (O/32); rem /= (O/32);
  int sp = rem % SP; int b = rem / SP;
  lutT[(tid & 15)*16 + (tid >> 4)] = (double)lut_g[tid];
  for (int i = tid; i < 4*KT; i += 256){
    int w2 = i / KT, k = i % KT;
    wps[i] = wp[(size_t)(ob*4 + w2)*(C*9) + (size_t)ks*KT + k];
  }
  for (int i = tid; i < CT*AH*AW; i += 256){
    int ct = i / (AH*AW);
    int r  = (i / AW) % AH;
    int cc = i % AW;
    int y = sp*ROWS + r - 1, x2 = cc - 1;
    uint8_t v = 8;  // zero-pad -> quant level 0 -> idx 8 (still contributes!)
    if (y >= 0 && y < H && x2 >= 0 && x2 < W)
      v = iain[(((size_t)b*C + ks*CT + ct)*H + y)*W + x2];
    acts[i] = v;
  }
  __syncthreads();
  int wid = tid >> 6, lane = tid & 63;
  int ly = lane / W, lx = lane % W;
  double acc[8] = {0,0,0,0,0,0,0,0};
  const uint32_t* wrow = &wps[wid*KT];
  #pragma unroll 1
  for (int ct = 0; ct < CT; ++ct){
    int abase = (ct*AH + ly)*AW + lx;
    #pragma unroll
    for (int ty = 0; ty < 3; ++ty)
    #pragma unroll
    for (int tx = 0; tx < 3; ++tx){
      int ia = acts[abase + ty*AW + tx];
      uint32_t sw = (uint32_t)__builtin_amdgcn_readfirstlane((int)wrow[ct*9 + ty*3 + tx]);
      #pragma unroll
      for (int j = 0; j < 8; ++j)
        acc[j] += lutT[((sw >> (4*j)) & 15u)*16 + ia];
    }
  }
  int y = sp*ROWS + ly;
  int obase = ob*32 + wid*8;
  #pragma unroll
  for (int j = 0; j < 8; ++j)
    atomicAdd(&P[(((size_t)b*O + obase + j)*H + y)*W + lx], acc[j]);
}

// P + bias + relu (+pool) + write act f64 + absmax.
template<int O, int Hc, int Wc, bool POOL>
__global__ __launch_bounds__(256) void k_post(
    const double* __restrict__ P, const float* __restrict__ bias,
    double* __restrict__ aout, double* slots, int sx_slot, int sw_slot, int ma_slot)
{
  constexpr int Ho = POOL ? Hc/2 : Hc, Wo = POOL ? Wc/2 : Wc;
  int i = blockIdx.x*256 + threadIdx.x;
  int x2 = i % Wo, y = (i / Wo) % Ho, o = (i / (Wo*Ho)) % O, b = i / (Wo*Ho*O);
  double scale = getscale(slots, sx_slot) * getscale(slots, sw_slot);
  double bo = (double)bias[o];
  double res;
  if (POOL){
    double p = 0.0;
    #pragma unroll
    for (int dy = 0; dy < 2; ++dy)
    #pragma unroll
    for (int dx = 0; dx < 2; ++dx){
      double s = P[(((size_t)b*O + o)*Hc + y*2+dy)*Wc + x2*2+dx];
      p = fmax(p, fmax(s*scale + bo, 0.0));
    }
    res = p;
  } else {
    double s = P[(((size_t)b*O + o)*Hc + y)*Wc + x2];
    res = fmax(s*scale + bo, 0.0);
  }
  aout[i] = res;
  double m = res;
  #pragma unroll
  for (int off = 32; off; off >>= 1) m = fmax(m, __shfl_xor(m, off, 64));
  __shared__ double red[4];
  if ((threadIdx.x & 63) == 0) red[threadIdx.x >> 6] = m;
  __syncthreads();
  if (threadIdx.x == 0)
    atomicMaxD(&slots[ma_slot], fmax(fmax(red[0],red[1]), fmax(red[2],red[3])));
}

__global__ __launch_bounds__(256) void k_aq_conv(
    const double* __restrict__ in, uint8_t* __restrict__ out,
    const double* slots, int slot, int n)
{
  int i = blockIdx.x*256 + threadIdx.x;
  if (i >= n) return;
  double rs = 1.0 / getscale(slots, slot);
  out[i] = (uint8_t)quant_idx_r(in[i], rs);
}

// fc-input quant: [b][4096] f64 -> per-f packed bytes lo(b0..3)/hi(b4..7).
__global__ __launch_bounds__(256) void k_aq_fc(
    const double* __restrict__ in, uint32_t* __restrict__ lo, uint32_t* __restrict__ hi,
    const double* slots, int slot)
{
  int f = blockIdx.x*256 + threadIdx.x; // 4096
  double rs = 1.0 / getscale(slots, slot);
  uint32_t l = 0, h = 0;
  #pragma unroll
  for (int b2 = 0; b2 < 4; ++b2) l |= (uint32_t)quant_idx_r(in[(size_t)b2*4096 + f], rs) << (8*b2);
  #pragma unroll
  for (int b2 = 4; b2 < 8; ++b2) h |= (uint32_t)quant_idx_r(in[(size_t)b2*4096 + f], rs) << (8*(b2-4));
  lo[f] = l; hi[f] = h;
}

// fc 4096->4096, 1 output/wave, f64 LDS LUT, on-the-fly weight quant.
template<bool RELU>
__global__ __launch_bounds__(256) void k_fc(
    const float* __restrict__ Wm, const float* __restrict__ bias,
    const uint32_t* __restrict__ ialo, const uint32_t* __restrict__ iahi,
    const float* __restrict__ lut_g, double* __restrict__ out,
    double* slots, int sx_slot, int sw_slot, int ma_slot)
{
  __shared__ double lutT[256];  // [iw][ia]
  __shared__ uint32_t los[4096], his[4096];
  __shared__ double red[4];
  int tid = threadIdx.x;
  lutT[(tid & 15)*16 + (tid >> 4)] = (double)lut_g[tid];
  for (int i = tid; i < 4096; i += 256){ los[i] = ialo[i]; his[i] = iahi[i]; }
  __syncthreads();
  double sw = getscale(slots, sw_slot);
  double rsw = 1.0 / sw;
  double scale = getscale(slots, sx_slot) * sw;
  int wid = tid >> 6, lane = tid & 63;
  int o = blockIdx.x*4 + wid;
  const float* wr = Wm + (size_t)o*4096;
  double acc[8] = {0,0,0,0,0,0,0,0};
  #pragma unroll 2
  for (int ch = 0; ch < 64; ++ch){
    int f = ch*64 + lane;
    unsigned iw = (unsigned)quant_idx_r((double)wr[f], rsw);
    const double* lrow = &lutT[iw << 4];
    uint32_t lo = los[f], hi = his[f];
    acc[0] += lrow[lo & 255];         acc[1] += lrow[(lo >> 8) & 255];
    acc[2] += lrow[(lo >> 16) & 255]; acc[3] += lrow[lo >> 24];
    acc[4] += lrow[hi & 255];         acc[5] += lrow[(hi >> 8) & 255];
    acc[6] += lrow[(hi >> 16) & 255]; acc[7] += lrow[hi >> 24];
  }
  #pragma unroll
  for (int off = 32; off; off >>= 1)
    #pragma unroll
    for (int b2 = 0; b2 < 8; ++b2) acc[b2] += __shfl_xor(acc[b2], off, 64);
  if (lane == 0){
    double m = 0.0;
    double bo = (double)bias[o];
    #pragma unroll
    for (int b2 = 0; b2 < 8; ++b2){
      double h = acc[b2]*scale + bo;
      if (RELU) h = fmax(h, 0.0);
      out[(size_t)b2*4096 + o] = h;
      m = fmax(m, fabs(h));
    }
    red[wid] = m;
  }
  __syncthreads();
  if (tid == 0)
    atomicMaxD(&slots[ma_slot], fmax(fmax(red[0],red[1]), fmax(red[2],red[3])));
}

// final fc 4096->10 (no relu), writes d_out [8,10] as f32.
__global__ __launch_bounds__(256) void k_fc7(
    const float* __restrict__ Wm, const float* __restrict__ bias,
    const uint32_t* __restrict__ ialo, const uint32_t* __restrict__ iahi,
    const float* __restrict__ lut_g, float* __restrict__ out, const double* slots)
{
  __shared__ double lutT[256];
  __shared__ uint32_t los[4096], his[4096];
  __shared__ double red[4][8];
  int tid = threadIdx.x;
  lutT[(tid & 15)*16 + (tid >> 4)] = (double)lut_g[tid];
  for (int i = tid; i < 4096; i += 256){ los[i] = ialo[i]; his[i] = iahi[i]; }
  __syncthreads();
  double sw = getscale(slots, 7);
  double rsw = 1.0 / sw;
  double scale = getscale(slots, 15) * sw;
  int o = blockIdx.x;
  const float* wr = Wm + (size_t)o*4096;
  double acc[8] = {0,0,0,0,0,0,0,0};
  for (int ch = 0; ch < 16; ++ch){
    int f = ch*256 + tid;
    unsigned iw = (unsigned)quant_idx_r((double)wr[f], rsw);
    const double* lrow = &lutT[iw << 4];
    uint32_t lo = los[f], hi = his[f];
    acc[0] += lrow[lo & 255];         acc[1] += lrow[(lo >> 8) & 255];
    acc[2] += lrow[(lo >> 16) & 255]; acc[3] += lrow[lo >> 24];
    acc[4] += lrow[hi & 255];         acc[5] += lrow[(hi >> 8) & 255];
    acc[6] += lrow[(hi >> 16) & 255]; acc[7] += lrow[hi >> 24];
  }
  int wid = tid >> 6, lane = tid & 63;
  #pragma unroll
  for (int off = 32; off; off >>= 1)
    #pragma unroll
    for (int b2 = 0; b2 < 8; ++b2) acc[b2] += __shfl_xor(acc[b2], off, 64);
  if (lane == 0){
    #pragma unroll
    for (int b2 = 0; b2 < 8; ++b2) red[wid][b2] = acc[b2];
  }
  __syncthreads();
  if (tid < 8){
    double v = red[0][tid] + red[1][tid] + red[2][tid] + red[3][tid];
    out[tid*10 + o] = (float)(v*scale + (double)bias[o]);
  }
}

// ---------------- launcher ----------------
extern "C" void kernel_launch(void* const* d_in, const int* in_sizes, int n_in,
                              void* d_out, int out_size, void* d_ws, size_t ws_size,
                              hipStream_t stream)
{
  (void)in_sizes; (void)n_in; (void)out_size; (void)ws_size;
  const float* x  = (const float*)d_in[0];
  const float* w0 = (const float*)d_in[1];  const float* b0 = (const float*)d_in[2];
  const float* w1 = (const float*)d_in[3];  const float* b1 = (const float*)d_in[4];
  const float* w2 = (const float*)d_in[5];  const float* b2 = (const float*)d_in[6];
  const float* w3 = (const float*)d_in[7];  const float* b3 = (const float*)d_in[8];
  const float* w4 = (const float*)d_in[9];  const float* b4 = (const float*)d_in[10];
  const float* w5 = (const float*)d_in[11]; const float* b5 = (const float*)d_in[12];
  const float* w6 = (const float*)d_in[13]; const float* b6 = (const float*)d_in[14];
  const float* w7 = (const float*)d_in[15]; const float* b7 = (const float*)d_in[16];
  const float* luts = (const float*)d_in[17];

  uint8_t* ws = (uint8_t*)d_ws;
  double* slots = (double*)(ws + O_SLOTS);
  const uint8_t* IA0 = ws + O_IA0;
  uint8_t *IA1 = ws + O_IA1, *IA2 = ws + O_IA2, *IA3 = ws + O_IA3, *IA4 = ws + O_IA4;
  uint32_t *IA5lo = (uint32_t*)(ws + O_IA5), *IA5hi = IA5lo + 4096;
  uint32_t *IA6lo = (uint32_t*)(ws + O_IA6), *IA6hi = IA6lo + 4096;
  uint32_t *IA7lo = (uint32_t*)(ws + O_IA7), *IA7hi = IA7lo + 4096;
  const uint32_t* WP0 = (const uint32_t*)(ws + O_WP0);
  const uint32_t* WP1 = (const uint32_t*)(ws + O_WP1);
  const uint32_t* WP2 = (const uint32_t*)(ws + O_WP2);
  const uint32_t* WP3 = (const uint32_t*)(ws + O_WP3);
  const uint32_t* WP4 = (const uint32_t*)(ws + O_WP4);
  double *A1 = (double*)(ws + O_A1), *A2 = (double*)(ws + O_A2), *A3 = (double*)(ws + O_A3);
  double *A4 = (double*)(ws + O_A4), *A5 = (double*)(ws + O_A5);
  double *H5 = (double*)(ws + O_H5), *H6 = (double*)(ws + O_H6);
  double *P1 = (double*)(ws + O_P1), *P2 = (double*)(ws + O_P2);
  double *P3 = (double*)(ws + O_P3), *P4 = (double*)(ws + O_P4);

  k_zero_all<<<833, 256, 0, stream>>>((double4*)(ws + O_P1), slots);
  k_wmax<<<1098, 256, 0, stream>>>(w0,w1,w2,w3,w4,w5,w6,w7,x,slots);
  k_wq<<<1123, 256, 0, stream>>>(w0,w1,w2,w3,w4,x,slots,ws);

  // L0: conv(3->64,32x32)+relu+pool -> A1 [8,64,16,16] f64, absmax->slot9
  k_conv0<<<512, 256, 0, stream>>>(IA0, WP0, luts + 0, b0, slots, A1);
  k_aq_conv<<<512, 256, 0, stream>>>(A1, IA1, slots, 9, 131072);

  // L1: conv(64->192,16x16)+pool. CT=8,KS=8,SP=4 -> grid 8*6*4*8=1536
  k_conv<64,192,16,16,8,4,4,8><<<1536, 256, 0, stream>>>(IA1, WP1, luts + 256, P1);
  k_post<192,16,16,true><<<384, 256, 0, stream>>>(P1, b1, A2, slots, 9, 1, 10);
  k_aq_conv<<<384, 256, 0, stream>>>(A2, IA2, slots, 10, 98304);

  // L2: conv(192->384,8x8). CT=12,KS=16 -> grid 8*12*16=1536
  k_conv<192,384,8,8,12,8,1,16><<<1536, 256, 0, stream>>>(IA2, WP2, luts + 512, P2);
  k_post<384,8,8,false><<<768, 256, 0, stream>>>(P2, b2, A3, slots, 10, 2, 11);
  k_aq_conv<<<768, 256, 0, stream>>>(A3, IA3, slots, 11, 196608);

  // L3: conv(384->256,8x8). CT=12,KS=32 -> grid 8*8*32=2048
  k_conv<384,256,8,8,12,8,1,32><<<2048, 256, 0, stream>>>(IA3, WP3, luts + 768, P3);
  k_post<256,8,8,false><<<512, 256, 0, stream>>>(P3, b3, A4, slots, 11, 3, 12);
  k_aq_conv<<<512, 256, 0, stream>>>(A4, IA4, slots, 12, 131072);

  // L4: conv(256->256,8x8)+pool. CT=8,KS=32 -> grid 8*8*32=2048
  k_conv<256,256,8,8,8,8,1,32><<<2048, 256, 0, stream>>>(IA4, WP4, luts + 1024, P4);
  k_post<256,8,8,true><<<128, 256, 0, stream>>>(P4, b4, A5, slots, 12, 4, 13);
  k_aq_fc<<<16, 256, 0, stream>>>(A5, IA5lo, IA5hi, slots, 13);

  // FC
  k_fc<true><<<1024, 256, 0, stream>>>(w5, b5, IA5lo, IA5hi, luts + 1280, H5, slots, 13, 5, 14);
  k_aq_fc<<<16, 256, 0, stream>>>(H5, IA6lo, IA6hi, slots, 14);
  k_fc<true><<<1024, 256, 0, stream>>>(w6, b6, IA6lo, IA6hi, luts + 1536, H6, slots, 14, 6, 15);
  k_aq_fc<<<16, 256, 0, stream>>>(H6, IA7lo, IA7hi, slots, 15);
  k_fc7<<<10, 256, 0, stream>>>(w7, b7, IA7lo, IA7hi, luts + 1792, (float*)d_out, slots);
}